// Round 1
// baseline (57.509 us; speedup 1.0000x reference)
//
#include <hip/hip_runtime.h>
#include <hip/hip_bf16.h>

// Problem constants
#define NTOK  8192      // 4*2048 tokens
#define KDIM  1024      // FEAT_DIM
#define NOUT  1024      // NUM_CODEBOOK * sum(CODE_DIMS) = 16*64
#define NCB   16

typedef __attribute__((ext_vector_type(8))) short short8;
typedef __attribute__((ext_vector_type(4))) float f32x4;

__device__ static inline unsigned short f2bf(float f) {
    unsigned int u = __float_as_uint(f);
    unsigned int r = (u + 0x7FFFu + ((u >> 16) & 1u)) >> 16;
    return (unsigned short)r;
}

__device__ static inline float bf2f(unsigned int h) {
    return __uint_as_float(h << 16);
}

__device__ static inline void async_copy16(const void* g, void* l) {
    __builtin_amdgcn_global_load_lds(
        (const __attribute__((address_space(1))) void*)g,
        (__attribute__((address_space(3))) void*)l, 16, 0, 0);
}

// ---------------- convert x: fp32 [8192][1024] -> bf16 A [8192][1024] ----------------
__global__ __launch_bounds__(256) void conv_x_kernel(const float* __restrict__ x,
                                                     unsigned short* __restrict__ A) {
    int u = blockIdx.x * 256 + threadIdx.x;   // exactly NTOK*KDIM/8 threads
    const float* src = x + (size_t)u * 8;
    float4 v0 = *(const float4*)(src);
    float4 v1 = *(const float4*)(src + 4);
    short8 o;
    o[0] = (short)f2bf(v0.x); o[1] = (short)f2bf(v0.y);
    o[2] = (short)f2bf(v0.z); o[3] = (short)f2bf(v0.w);
    o[4] = (short)f2bf(v1.x); o[5] = (short)f2bf(v1.y);
    o[6] = (short)f2bf(v1.z); o[7] = (short)f2bf(v1.w);
    *(short8*)(A + (size_t)u * 8) = o;
}

// ---------------- convert weight: fp32 [16][1024][64] -> bf16 Bt [1024][1024] ----------------
// Bt[n][k] = W[h][k][o],  n = h*64+o
__global__ __launch_bounds__(256) void conv_w_kernel(const float* __restrict__ W,
                                                     unsigned short* __restrict__ Bt) {
    int u = blockIdx.x * 256 + threadIdx.x;   // exactly NOUT * KDIM/8 threads
    int n  = u & (NOUT - 1);
    int k0 = (u >> 10) << 3;
    int h = n >> 6, o = n & 63;
    const float* src = W + (size_t)h * KDIM * 64 + o;
    short8 v;
#pragma unroll
    for (int j = 0; j < 8; ++j)
        v[j] = (short)f2bf(src[(size_t)(k0 + j) * 64]);
    *(short8*)(Bt + (size_t)n * KDIM + k0) = v;
}

// ---------------- GEMM: Y[m][n] = sum_k A[m][k]*Bt[n][k], bf16 in, bf16 out ----------------
// 128x128 tile, BK=32, 256 threads = 4 waves (2x2 of 64x64), mfma 16x16x32 bf16.
__global__ __launch_bounds__(256) void gemm_kernel(const unsigned short* __restrict__ A,
                                                   const unsigned short* __restrict__ Bt,
                                                   unsigned short* __restrict__ Y) {
    __shared__ unsigned short Alds[128 * 32];
    __shared__ unsigned short Blds[128 * 32];

    const int tid = threadIdx.x;
    const int m0 = blockIdx.y * 128;
    const int n0 = blockIdx.x * 128;
    const int lane = tid & 63;
    const int w = tid >> 6;
    const int wr = (w >> 1) * 64;   // wave row offset in tile
    const int wc = (w & 1) * 64;    // wave col offset in tile
    const int r15 = lane & 15;
    const int kq = (lane >> 4) * 8; // k sub-offset within BK=32

    f32x4 acc[4][4];
#pragma unroll
    for (int m = 0; m < 4; ++m)
#pragma unroll
        for (int n = 0; n < 4; ++n)
            acc[m][n] = (f32x4){0.f, 0.f, 0.f, 0.f};

    const unsigned short* Ag = A + (size_t)m0 * KDIM;
    const unsigned short* Bg = Bt + (size_t)n0 * KDIM;

    for (int kt = 0; kt < KDIM; kt += 32) {
        // stage 128x32 A tile and 128x32 Bt tile; 16B per lane per issue
#pragma unroll
        for (int issue = 0; issue < 2; ++issue) {
            int e = (issue * 256 + tid) * 8;   // element offset in tile
            int row = e >> 5;                  // /32
            int kk = e & 31;
            async_copy16(Ag + (size_t)row * KDIM + kt + kk, Alds + e);
            async_copy16(Bg + (size_t)row * KDIM + kt + kk, Blds + e);
        }
        __syncthreads();

        short8 af[4], bf[4];
#pragma unroll
        for (int m = 0; m < 4; ++m)
            af[m] = *(const short8*)&Alds[(wr + m * 16 + r15) * 32 + kq];
#pragma unroll
        for (int n = 0; n < 4; ++n)
            bf[n] = *(const short8*)&Blds[(wc + n * 16 + r15) * 32 + kq];

#pragma unroll
        for (int m = 0; m < 4; ++m)
#pragma unroll
            for (int n = 0; n < 4; ++n)
                acc[m][n] = __builtin_amdgcn_mfma_f32_16x16x32_bf16(af[m], bf[n], acc[m][n], 0, 0, 0);
        __syncthreads();
    }

    // write back: D layout col=lane&15, row=(lane>>4)*4+r
    const int rrow = (lane >> 4) * 4;
#pragma unroll
    for (int m = 0; m < 4; ++m) {
#pragma unroll
        for (int n = 0; n < 4; ++n) {
            int col = n0 + wc + n * 16 + r15;
#pragma unroll
            for (int r = 0; r < 4; ++r) {
                int row = m0 + wr + m * 16 + rrow + r;
                Y[(size_t)row * NOUT + col] = f2bf(acc[m][n][r]);
            }
        }
    }
}

// ---------------- epilogue: outer product + mean*sqrt(h) + rms_norm ----------------
// one block (256 threads) per token; y row (1024 bf16) staged in LDS as fp32
__global__ __launch_bounds__(256) void epilogue_kernel(const unsigned short* __restrict__ Y,
                                                       float* __restrict__ out) {
    __shared__ float ylds[1024];
    __shared__ float red[4];

    const int t = blockIdx.x;
    const int tid = threadIdx.x;
    const unsigned short* yrow = Y + (size_t)t * NOUT;

    {
        uint2 raw = *(const uint2*)(yrow + tid * 4);
        ylds[tid * 4 + 0] = bf2f(raw.x & 0xffffu);
        ylds[tid * 4 + 1] = bf2f(raw.x >> 16);
        ylds[tid * 4 + 2] = bf2f(raw.y & 0xffffu);
        ylds[tid * 4 + 3] = bf2f(raw.y >> 16);
    }
    __syncthreads();

    const int j = tid >> 3;            // 0..31 (first-factor index)
    const int k0 = (tid & 7) * 4;      // 0,4,...,28 (second-factor base)

    float o0 = 0.f, o1 = 0.f, o2 = 0.f, o3 = 0.f;
#pragma unroll
    for (int h = 0; h < NCB; ++h) {
        float a = ylds[h * 64 + j];
        float4 b = *(const float4*)&ylds[h * 64 + 32 + k0];
        o0 += a * b.x; o1 += a * b.y; o2 += a * b.z; o3 += a * b.w;
    }
    o0 *= 0.25f; o1 *= 0.25f; o2 *= 0.25f; o3 *= 0.25f;  // mean * sqrt(16)

    float ss = o0 * o0 + o1 * o1 + o2 * o2 + o3 * o3;
#pragma unroll
    for (int off = 32; off >= 1; off >>= 1)
        ss += __shfl_xor(ss, off, 64);

    const int lane = tid & 63, w = tid >> 6;
    if (lane == 0) red[w] = ss;
    __syncthreads();
    float tot = red[0] + red[1] + red[2] + red[3];
    float scale = rsqrtf(tot * (1.0f / 1024.0f) + 1e-12f);

    float4 o;
    o.x = o0 * scale; o.y = o1 * scale; o.z = o2 * scale; o.w = o3 * scale;
    *(float4*)(out + (size_t)t * 1024 + tid * 4) = o;
}

extern "C" void kernel_launch(void* const* d_in, const int* in_sizes, int n_in,
                              void* d_out, int out_size, void* d_ws, size_t ws_size,
                              hipStream_t stream) {
    const float* x = (const float*)d_in[0];
    const float* wgt = (const float*)d_in[1];
    float* out = (float*)d_out;

    unsigned short* A  = (unsigned short*)d_ws;                        // 16 MB
    unsigned short* Bt = (unsigned short*)((char*)d_ws + (16u << 20)); //  2 MB
    unsigned short* Y  = (unsigned short*)((char*)d_ws + (18u << 20)); // 16 MB

    conv_x_kernel<<<NTOK * KDIM / 8 / 256, 256, 0, stream>>>(x, A);
    conv_w_kernel<<<NOUT * KDIM / 8 / 256, 256, 0, stream>>>(wgt, Bt);
    gemm_kernel<<<dim3(NOUT / 128, NTOK / 128), 256, 0, stream>>>(A, Bt, Y);
    epilogue_kernel<<<NTOK, 256, 0, stream>>>(Y, out);
}